// Round 6
// baseline (274.630 us; speedup 1.0000x reference)
//
#include <hip/hip_runtime.h>
#include <hip/hip_bf16.h>
#include <cstdint>
#include <math.h>

#define SEQ 2048
#define BATCH 2
#define HID 1024
#define NH 16
#define HD 64
#define MROWS (SEQ * BATCH)  // 4096

typedef __attribute__((ext_vector_type(8))) short bf16x8;
typedef __attribute__((ext_vector_type(4))) float f32x4;

typedef const __attribute__((address_space(1))) void* gas_t;
typedef __attribute__((address_space(3))) void* las_t;

static __device__ __forceinline__ unsigned short f2bf(float x) {
    __hip_bfloat16 h = __float2bfloat16(x);  // RTNE
    unsigned short u;
    __builtin_memcpy(&u, &h, 2);
    return u;
}

// ---------------------------------------------------------------------------
// fp32 -> bf16 conversion, 8 elements/thread
// ---------------------------------------------------------------------------
__global__ __launch_bounds__(256) void f2bf_kern(const float* __restrict__ in,
                                                 unsigned short* __restrict__ out,
                                                 int n8) {
    int i = blockIdx.x * 256 + threadIdx.x;
    if (i >= n8) return;
    const float4* p = (const float4*)in + (size_t)i * 2;
    float4 a = p[0], b = p[1];
    union { unsigned short us[8]; uint4 v; } o;
    o.us[0] = f2bf(a.x); o.us[1] = f2bf(a.y); o.us[2] = f2bf(a.z); o.us[3] = f2bf(a.w);
    o.us[4] = f2bf(b.x); o.us[5] = f2bf(b.y); o.us[6] = f2bf(b.z); o.us[7] = f2bf(b.w);
    ((uint4*)out)[i] = o.v;
}

// ---------------------------------------------------------------------------
// bf16 MFMA GEMM, m97 structure: BM=128, BN=32*BNT2 (template), BK=32.
// 256 thr = 4 waves (2x2); wave tile 64 x (16*BNT2); acc 4 x BNT2 frags.
// BNT2=4 -> BN=128, 16 MFMA : 8 ds_read_b128 per wave-iter (m97 ratio).
// BNT2=2 -> BN=64 (for Wo: more blocks at N=1024).
// Double-buffered LDS, single-barrier prefetch: stage(k+1) after barrier,
// before compute(k); next barrier's implicit vmcnt(0) drain is the wait.
// mode 0 (QKV fused, N=3072): seg 0 -> Q bf16 [m][1024] scaled 1/8,
//   seg 1 -> K bf16 [m][1024], seg 2 -> V^T bf16 [n][b][s] (m = s*2+b).
// mode 1 (Wo): fp32 [m][1024], bias b0.
// ---------------------------------------------------------------------------
#define GBK 32

template <int BNT2>
__global__ __launch_bounds__(256) void gemm_bf16(
    const unsigned short* __restrict__ A, const unsigned short* __restrict__ W,
    const float* __restrict__ b0, const float* __restrict__ b1,
    const float* __restrict__ b2,
    unsigned short* __restrict__ Qo, unsigned short* __restrict__ Ko,
    unsigned short* __restrict__ Vo, float* __restrict__ Fo, int mode) {
    constexpr int BN = BNT2 * 32;
    __shared__ unsigned short As[2][128 * GBK];   // [m][k] 8KB each
    __shared__ unsigned short Bs[2][BN * GBK];    // [n][k]
    const int t = threadIdx.x;
    const int lane = t & 63, w = t >> 6;
    const int wr = w & 1, wc = w >> 1;
    const int m0 = blockIdx.x * 128, n0 = blockIdx.y * BN;

    f32x4 acc[4][BNT2];
#pragma unroll
    for (int i = 0; i < 4; ++i)
#pragma unroll
        for (int j = 0; j < BNT2; ++j) acc[i][j] = {0.f, 0.f, 0.f, 0.f};

    // staging: per call, wave w covers rows c*64 + w*16 + (lane>>2), 16B chunk lane&3
    const unsigned short* gA = A + (size_t)(m0 + w * 16 + (lane >> 2)) * HID + (lane & 3) * 8;
    const unsigned short* gB = W + (size_t)(n0 + w * 16 + (lane >> 2)) * HID + (lane & 3) * 8;

    auto stage = [&](int buf, int k0) {
#pragma unroll
        for (int c = 0; c < 2; ++c)
            __builtin_amdgcn_global_load_lds((gas_t)(gA + (size_t)c * 64 * HID + k0),
                                             (las_t)(&As[buf][(c * 64 + w * 16) * GBK]), 16, 0, 0);
#pragma unroll
        for (int c = 0; c < BN / 64; ++c)
            __builtin_amdgcn_global_load_lds((gas_t)(gB + (size_t)c * 64 * HID + k0),
                                             (las_t)(&Bs[buf][(c * 64 + w * 16) * GBK]), 16, 0, 0);
    };

    const int arow = wr * 64 + (lane & 15);
    const int brow = wc * (BNT2 * 16) + (lane & 15);
    const int kfo = (lane >> 4) * 8;

    stage(0, 0);
    int cur = 0;
    for (int k0 = 0; k0 < HID; k0 += GBK) {
        __syncthreads();  // drains vmcnt: buf[cur] staged; buf[cur^1] reads done
        if (k0 + GBK < HID) stage(cur ^ 1, k0 + GBK);
        bf16x8 af[4], bfr[BNT2];
#pragma unroll
        for (int mt = 0; mt < 4; ++mt)
            af[mt] = *(const bf16x8*)(&As[cur][(arow + mt * 16) * GBK + kfo]);
#pragma unroll
        for (int nt = 0; nt < BNT2; ++nt)
            bfr[nt] = *(const bf16x8*)(&Bs[cur][(brow + nt * 16) * GBK + kfo]);
#pragma unroll
        for (int mt = 0; mt < 4; ++mt)
#pragma unroll
            for (int nt = 0; nt < BNT2; ++nt)
                acc[mt][nt] = __builtin_amdgcn_mfma_f32_16x16x32_bf16(
                    af[mt], bfr[nt], acc[mt][nt], 0, 0, 0);
        cur ^= 1;
    }

    // ---- epilogue: segment-uniform per block (BN divides 1024) ----
    const int seg = n0 >> 10;  // 0=Q 1=K 2=V (mode 0); 0 for mode 1
    const float* bias = (mode == 1) ? b0 : (seg == 0 ? b0 : (seg == 1 ? b1 : b2));
    const float scale = (mode == 0 && seg == 0) ? 0.125f : 1.0f;
    const int nbase = (n0 & 1023) + wc * (BNT2 * 16);

    float bvals[BNT2];
#pragma unroll
    for (int nt = 0; nt < BNT2; ++nt)
        bvals[nt] = bias[nbase + nt * 16 + (lane & 15)];

#pragma unroll
    for (int mt = 0; mt < 4; ++mt)
#pragma unroll
        for (int nt = 0; nt < BNT2; ++nt)
#pragma unroll
            for (int i = 0; i < 4; ++i) {
                float v = (acc[mt][nt][i] + bvals[nt]) * scale;
                int m = m0 + wr * 64 + mt * 16 + (lane >> 4) * 4 + i;
                int n = nbase + nt * 16 + (lane & 15);  // within-segment col
                if (mode == 1) {
                    Fo[(size_t)m * HID + n] = v;
                } else if (seg == 0) {
                    Qo[(size_t)m * HID + n] = f2bf(v);
                } else if (seg == 1) {
                    Ko[(size_t)m * HID + n] = f2bf(v);
                } else {
                    Vo[(size_t)n * MROWS + (m & 1) * SEQ + (m >> 1)] = f2bf(v);
                }
            }
}

// ---------------------------------------------------------------------------
// Flash causal attention, bf16 MFMA (R4 pipeline), occupancy-maximized:
// grid (32, 32) = 1024 blocks, one q-tile each; 40KB LDS -> exactly 4
// blocks/CU -> ALL blocks co-resident (no dispatch tail), 4 waves/SIMD.
// K/V double-buffered, staged via global_load_lds with pre-swizzled global
// source (linear dest + inverse-swz src + swz read; byte^=(row&7)<<4).
// One __syncthreads()/iter. XCD-clustered bh mapping (4 bh per XCD).
// ---------------------------------------------------------------------------
__global__ __launch_bounds__(256) void attn_mfma(const unsigned short* __restrict__ Qb,
                                                 const unsigned short* __restrict__ Kb,
                                                 const unsigned short* __restrict__ Vt,
                                                 unsigned short* __restrict__ Ob) {
    __shared__ unsigned short Kl[2][64 * 64];  // [j][d] swizzled, 8KB each
    __shared__ unsigned short Vl[2][64 * 64];  // [d][j] swizzled, 8KB each
    __shared__ unsigned short QP[64 * 64];     // Q then P, swizzled, 8KB

    const int t = threadIdx.x;
    const int lane = t & 63, w = t >> 6;

    // XCD-clustered mapping: 4 bh per XCD (4 x 512KB KV = 2MB < 4MB L2)
    const int flat = (int)blockIdx.x + (int)blockIdx.y * 32;
    const int xcd = flat & 7, ii = flat >> 3;        // ii in [0,128)
    const int bh = xcd * 4 + (ii >> 5);
    const int qt = 31 - (ii & 31);                   // heavy tiles first
    const int b = bh >> 4, h = bh & 15;
    const int q0 = qt * 64;

    const int lrow_base = w * 8 + (lane >> 3);
    const int chunkb = (lane & 7) * 16;

    auto stage_kv = [&](int buf, int kt) {
        const int k0 = kt * 64;
#pragma unroll
        for (int c = 0; c < 2; ++c) {
            int lr = c * 32 + lrow_base;
            int sb = chunkb ^ ((lr & 7) << 4);
            const unsigned short* ksrc =
                Kb + ((size_t)(k0 + lr) * 2 + b) * HID + h * 64 + (sb >> 1);
            const unsigned short* vsrc =
                Vt + (size_t)(h * 64 + lr) * MROWS + b * SEQ + k0 + (sb >> 1);
            __builtin_amdgcn_global_load_lds((gas_t)ksrc,
                (las_t)(&Kl[buf][(c * 32 + w * 8) * 64]), 16, 0, 0);
            __builtin_amdgcn_global_load_lds((gas_t)vsrc,
                (las_t)(&Vl[buf][(c * 32 + w * 8) * 64]), 16, 0, 0);
        }
    };

    stage_kv(0, 0);  // in flight during Q staging

    // ---- stage Q tile (reg -> swizzled LDS) ----
#pragma unroll
    for (int c = 0; c < 2; ++c) {
        int f = c * 256 + t;
        int r = f >> 3, dc = f & 7;
        uint4 v = *(const uint4*)(Qb + (size_t)((q0 + r) * 2 + b) * HID + h * 64 + dc * 8);
        *(uint4*)((char*)QP + r * 128 + ((dc * 16) ^ ((r & 7) << 4))) = v;
    }

    f32x4 acc[4];
#pragma unroll
    for (int nt = 0; nt < 4; ++nt) acc[nt] = {0.f, 0.f, 0.f, 0.f};
    float mrow[4] = {-INFINITY, -INFINITY, -INFINITY, -INFINITY};
    float lrow[4] = {0.f, 0.f, 0.f, 0.f};
    bf16x8 qf[2];

    int cur = 0;
    for (int kt = 0; kt <= qt; ++kt) {
        __syncthreads();  // drains vmcnt (Kl/Vl[cur] staged) + lgkm (Q/P writes)
        if (kt < qt) stage_kv(cur ^ 1, kt + 1);
        if (kt == 0) {
            int r = w * 16 + (lane & 15);
            int base = r * 128, sw = (r & 7) << 4;
            qf[0] = *(const bf16x8*)((char*)QP + base + ((((lane >> 4) * 16) + 0) ^ sw));
            qf[1] = *(const bf16x8*)((char*)QP + base + ((((lane >> 4) * 16) + 64) ^ sw));
        }
        const char* Kc = (const char*)Kl[cur];
        const char* Vc = (const char*)Vl[cur];

        // ---- S = Q K^T ----
        f32x4 s[4];
#pragma unroll
        for (int ct = 0; ct < 4; ++ct) {
            int j = ct * 16 + (lane & 15);
            int base = j * 128, sw = (j & 7) << 4;
            bf16x8 kf0 = *(const bf16x8*)(Kc + base + ((((lane >> 4) * 16) + 0) ^ sw));
            bf16x8 kf1 = *(const bf16x8*)(Kc + base + ((((lane >> 4) * 16) + 64) ^ sw));
            f32x4 z = {0.f, 0.f, 0.f, 0.f};
            z = __builtin_amdgcn_mfma_f32_16x16x32_bf16(qf[0], kf0, z, 0, 0, 0);
            z = __builtin_amdgcn_mfma_f32_16x16x32_bf16(qf[1], kf1, z, 0, 0, 0);
            s[ct] = z;
        }

        // ---- causal mask on diagonal tile ----
        if (kt == qt) {
#pragma unroll
            for (int ct = 0; ct < 4; ++ct) {
                int j = ct * 16 + (lane & 15);
#pragma unroll
                for (int i = 0; i < 4; ++i) {
                    int q = w * 16 + (lane >> 4) * 4 + i;
                    if (j > q) s[ct][i] = -3.0e38f;
                }
            }
        }

        // ---- online softmax (row lives in 16 consecutive lanes) ----
#pragma unroll
        for (int i = 0; i < 4; ++i) {
            float mx = fmaxf(fmaxf(s[0][i], s[1][i]), fmaxf(s[2][i], s[3][i]));
            mx = fmaxf(mx, __shfl_xor(mx, 1));
            mx = fmaxf(mx, __shfl_xor(mx, 2));
            mx = fmaxf(mx, __shfl_xor(mx, 4));
            mx = fmaxf(mx, __shfl_xor(mx, 8));
            float mn = fmaxf(mrow[i], mx);
            float corr = __expf(mrow[i] - mn);
            mrow[i] = mn;
            float rs = 0.f;
#pragma unroll
            for (int ct = 0; ct < 4; ++ct) {
                float pe = __expf(s[ct][i] - mn);
                s[ct][i] = pe;
                rs += pe;
            }
            rs += __shfl_xor(rs, 1);
            rs += __shfl_xor(rs, 2);
            rs += __shfl_xor(rs, 4);
            rs += __shfl_xor(rs, 8);
            lrow[i] = lrow[i] * corr + rs;
#pragma unroll
            for (int nt = 0; nt < 4; ++nt) acc[nt][i] *= corr;
        }

        // ---- P -> bf16 -> LDS (wave-private rows of QP) ----
#pragma unroll
        for (int ct = 0; ct < 4; ++ct)
#pragma unroll
            for (int i = 0; i < 4; ++i) {
                int r = w * 16 + (lane >> 4) * 4 + i;
                int jb = (ct * 16 + (lane & 15)) * 2;
                *(unsigned short*)((char*)QP + r * 128 + (jb ^ ((r & 7) << 4))) = f2bf(s[ct][i]);
            }
        asm volatile("s_waitcnt lgkmcnt(0)" ::: "memory");
        __builtin_amdgcn_sched_barrier(0);

        // ---- O += P V ----
        bf16x8 pf[2];
        {
            int r = w * 16 + (lane & 15);
            int base = r * 128, sw = (r & 7) << 4;
            pf[0] = *(const bf16x8*)((char*)QP + base + ((((lane >> 4) * 16) + 0) ^ sw));
            pf[1] = *(const bf16x8*)((char*)QP + base + ((((lane >> 4) * 16) + 64) ^ sw));
        }
#pragma unroll
        for (int nt = 0; nt < 4; ++nt) {
            int d = nt * 16 + (lane & 15);
            int base = d * 128, sw = (d & 7) << 4;
            bf16x8 v0 = *(const bf16x8*)(Vc + base + ((((lane >> 4) * 16) + 0) ^ sw));
            bf16x8 v1 = *(const bf16x8*)(Vc + base + ((((lane >> 4) * 16) + 64) ^ sw));
            acc[nt] = __builtin_amdgcn_mfma_f32_16x16x32_bf16(pf[0], v0, acc[nt], 0, 0, 0);
            acc[nt] = __builtin_amdgcn_mfma_f32_16x16x32_bf16(pf[1], v1, acc[nt], 0, 0, 0);
        }
        cur ^= 1;
    }

    // ---- normalize, write context ----
#pragma unroll
    for (int i = 0; i < 4; ++i) {
        float inv = 1.0f / lrow[i];
        int q = q0 + w * 16 + (lane >> 4) * 4 + i;
#pragma unroll
        for (int nt = 0; nt < 4; ++nt) {
            int col = h * 64 + nt * 16 + (lane & 15);
            Ob[(size_t)(q * 2 + b) * HID + col] = f2bf(acc[nt][i] * inv);
        }
    }
}

// ---------------------------------------------------------------------------
// Workspace (48 MB): hs_bf 8 | Wqkv_bf 6 | Wo_bf 2 | Q_bf 8 | K_bf 8 |
// Vt_bf 8 | ctx_bf 8
// ---------------------------------------------------------------------------
extern "C" void kernel_launch(void* const* d_in, const int* in_sizes, int n_in,
                              void* d_out, int out_size, void* d_ws, size_t ws_size,
                              hipStream_t stream) {
    const float* hs = (const float*)d_in[0];
    const float* Wq = (const float*)d_in[2];
    const float* bq = (const float*)d_in[3];
    const float* Wk = (const float*)d_in[4];
    const float* bk = (const float*)d_in[5];
    const float* Wv = (const float*)d_in[6];
    const float* bv = (const float*)d_in[7];
    const float* Wo = (const float*)d_in[8];
    const float* bo = (const float*)d_in[9];

    char* ws = (char*)d_ws;
    unsigned short* hs_bf   = (unsigned short*)(ws);
    unsigned short* Wqkv_bf = (unsigned short*)(ws + (8u << 20));   // 3072x1024
    unsigned short* Wo_bf   = (unsigned short*)(ws + (14u << 20));
    unsigned short* Q_bf    = (unsigned short*)(ws + (16u << 20));
    unsigned short* K_bf    = (unsigned short*)(ws + (24u << 20));
    unsigned short* Vt_bf   = (unsigned short*)(ws + (32u << 20));
    unsigned short* ctx_bf  = (unsigned short*)(ws + (40u << 20));

    dim3 blk(256);
    const int WN8 = HID * HID / 8;
    hipLaunchKernelGGL(f2bf_kern, dim3(MROWS * HID / 8 / 256), blk, 0, stream, hs, hs_bf, MROWS * HID / 8);
    hipLaunchKernelGGL(f2bf_kern, dim3(WN8 / 256), blk, 0, stream, Wq, Wqkv_bf, WN8);
    hipLaunchKernelGGL(f2bf_kern, dim3(WN8 / 256), blk, 0, stream, Wk, Wqkv_bf + (size_t)HID * HID, WN8);
    hipLaunchKernelGGL(f2bf_kern, dim3(WN8 / 256), blk, 0, stream, Wv, Wqkv_bf + (size_t)2 * HID * HID, WN8);
    hipLaunchKernelGGL(f2bf_kern, dim3(WN8 / 256), blk, 0, stream, Wo, Wo_bf, WN8);

    // fused QKV projection: BM=BN=128, grid (32,24) = 768 blocks (3/CU)
    hipLaunchKernelGGL((gemm_bf16<4>), dim3(MROWS / 128, 24), blk, 0, stream,
                       hs_bf, Wqkv_bf, bq, bk, bv, Q_bf, K_bf, Vt_bf, (float*)nullptr, 0);

    hipLaunchKernelGGL(attn_mfma, dim3(32, 32), blk, 0, stream,
                       Q_bf, K_bf, Vt_bf, ctx_bf);

    // output projection: BM=128 BN=64, grid (32,16) = 512 blocks (2/CU)
    hipLaunchKernelGGL((gemm_bf16<2>), dim3(MROWS / 128, 16), blk, 0, stream,
                       ctx_bf, Wo_bf, bo, bo, bo,
                       (unsigned short*)nullptr, (unsigned short*)nullptr,
                       (unsigned short*)nullptr, (float*)d_out, 1);
}

// Round 7
// 249.727 us; speedup vs baseline: 1.0997x; 1.0997x over previous
//
#include <hip/hip_runtime.h>
#include <hip/hip_bf16.h>
#include <cstdint>
#include <math.h>

#define SEQ 2048
#define BATCH 2
#define HID 1024
#define NH 16
#define HD 64
#define MROWS (SEQ * BATCH)  // 4096

typedef __attribute__((ext_vector_type(8))) short bf16x8;
typedef __attribute__((ext_vector_type(4))) float f32x4;

typedef const __attribute__((address_space(1))) void* gas_t;
typedef __attribute__((address_space(3))) void* las_t;

static __device__ __forceinline__ unsigned short f2bf(float x) {
    __hip_bfloat16 h = __float2bfloat16(x);  // RTNE
    unsigned short u;
    __builtin_memcpy(&u, &h, 2);
    return u;
}

// ---------------------------------------------------------------------------
// fp32 -> bf16 conversion, 8 elements/thread
// ---------------------------------------------------------------------------
__global__ __launch_bounds__(256) void f2bf_kern(const float* __restrict__ in,
                                                 unsigned short* __restrict__ out,
                                                 int n8) {
    int i = blockIdx.x * 256 + threadIdx.x;
    if (i >= n8) return;
    const float4* p = (const float4*)in + (size_t)i * 2;
    float4 a = p[0], b = p[1];
    union { unsigned short us[8]; uint4 v; } o;
    o.us[0] = f2bf(a.x); o.us[1] = f2bf(a.y); o.us[2] = f2bf(a.z); o.us[3] = f2bf(a.w);
    o.us[4] = f2bf(b.x); o.us[5] = f2bf(b.y); o.us[6] = f2bf(b.z); o.us[7] = f2bf(b.w);
    ((uint4*)out)[i] = o.v;
}

// ---------------------------------------------------------------------------
// bf16 MFMA GEMM, depth-3 counted-vmcnt pipeline (T4).
// BM=128, BN=32*BNT2, BK=32; 256 thr = 4 waves (2x2); wave tile 64x(16*BNT2).
// 3 LDS buffers; prologue stages tiles 0,1,2 (3*LOADS vm-ops in flight);
// iter t: s_waitcnt vmcnt(2*LOADS)  -> only tile t's loads drained
//         s_barrier -> ds_read + MFMA -> lgkmcnt(0) -> s_barrier
//         -> restage consumed buffer with tile t+3.
// Tail peels t=30 (vmcnt(LOADS)) and t=31 (vmcnt(0)).
// XCD-clustered grid mapping: dispatch id d -> xcd d&7 owns gridDim.y/8
// consecutive n-panels (B-panel reuse stays in one XCD's L2).
// mode 0 (QKV fused, N=3072): seg 0 -> Q bf16 [m][1024] scaled 1/8,
//   seg 1 -> K bf16, seg 2 -> V^T bf16 [n][b][s] (m = s*2+b).
// mode 1 (Wo): fp32 [m][1024], bias b0.
// ---------------------------------------------------------------------------
#define GBK 32
#define NT (HID / GBK)  // 32 K-tiles

template <int BNT2>
__global__ __launch_bounds__(256) void gemm_bf16(
    const unsigned short* __restrict__ A, const unsigned short* __restrict__ W,
    const float* __restrict__ b0, const float* __restrict__ b1,
    const float* __restrict__ b2,
    unsigned short* __restrict__ Qo, unsigned short* __restrict__ Ko,
    unsigned short* __restrict__ Vo, float* __restrict__ Fo, int mode) {
    constexpr int BN = BNT2 * 32;
    constexpr int LOADS = 2 + BN / 64;  // vm-ops per stage()
    __shared__ unsigned short As[3][128 * GBK];  // [m][k] 8KB each
    __shared__ unsigned short Bs[3][BN * GBK];   // [n][k]
    const int t = threadIdx.x;
    const int lane = t & 63, w = t >> 6;
    const int wr = w & 1, wc = w >> 1;

    // XCD-clustered remap: d -> (bx, by) with gridDim.y/8 panels per XCD
    const int d = (int)blockIdx.x + (int)blockIdx.y * (int)gridDim.x;
    const int ppx = (int)gridDim.y >> 3;            // panels per XCD
    const int xcd = d & 7, slot = d >> 3;           // slot in [0, gridDim.x*ppx)
    const int by = xcd * ppx + (slot >> 5);         // gridDim.x == 32
    const int bx = slot & 31;
    const int m0 = bx * 128, n0 = by * BN;

    f32x4 acc[4][BNT2];
#pragma unroll
    for (int i = 0; i < 4; ++i)
#pragma unroll
        for (int j = 0; j < BNT2; ++j) acc[i][j] = {0.f, 0.f, 0.f, 0.f};

    // staging: wave w covers rows c*64 + w*16 + (lane>>2), 16B chunk lane&3
    const unsigned short* gA = A + (size_t)(m0 + w * 16 + (lane >> 2)) * HID + (lane & 3) * 8;
    const unsigned short* gB = W + (size_t)(n0 + w * 16 + (lane >> 2)) * HID + (lane & 3) * 8;

    auto stage = [&](int buf, int kt) {
        const int k0 = kt * GBK;
#pragma unroll
        for (int c = 0; c < 2; ++c)
            __builtin_amdgcn_global_load_lds((gas_t)(gA + (size_t)c * 64 * HID + k0),
                                             (las_t)(&As[buf][(c * 64 + w * 16) * GBK]), 16, 0, 0);
#pragma unroll
        for (int c = 0; c < BN / 64; ++c)
            __builtin_amdgcn_global_load_lds((gas_t)(gB + (size_t)c * 64 * HID + k0),
                                             (las_t)(&Bs[buf][(c * 64 + w * 16) * GBK]), 16, 0, 0);
    };

    const int arow = wr * 64 + (lane & 15);
    const int brow = wc * (BNT2 * 16) + (lane & 15);
    const int kfo = (lane >> 4) * 8;

    stage(0, 0); stage(1, 1); stage(2, 2);
    int bn = 0;
    for (int kt = 0; kt < NT; ++kt) {
        if (kt <= NT - 3)
            asm volatile("s_waitcnt vmcnt(%0)" :: "n"(2 * LOADS) : "memory");
        else if (kt == NT - 2)
            asm volatile("s_waitcnt vmcnt(%0)" :: "n"(LOADS) : "memory");
        else
            asm volatile("s_waitcnt vmcnt(0)" ::: "memory");
        __builtin_amdgcn_s_barrier();  // buf[bn] staged for ALL waves

        bf16x8 af[4], bfr[BNT2];
#pragma unroll
        for (int mt = 0; mt < 4; ++mt)
            af[mt] = *(const bf16x8*)(&As[bn][(arow + mt * 16) * GBK + kfo]);
#pragma unroll
        for (int nt = 0; nt < BNT2; ++nt)
            bfr[nt] = *(const bf16x8*)(&Bs[bn][(brow + nt * 16) * GBK + kfo]);
#pragma unroll
        for (int mt = 0; mt < 4; ++mt)
#pragma unroll
            for (int nt = 0; nt < BNT2; ++nt)
                acc[mt][nt] = __builtin_amdgcn_mfma_f32_16x16x32_bf16(
                    af[mt], bfr[nt], acc[mt][nt], 0, 0, 0);

        asm volatile("s_waitcnt lgkmcnt(0)" ::: "memory");  // own ds_reads done
        __builtin_amdgcn_sched_barrier(0);
        __builtin_amdgcn_s_barrier();  // all waves' reads done -> overwrite ok
        if (kt + 3 < NT) stage(bn, kt + 3);
        bn = (bn == 2) ? 0 : bn + 1;
    }

    // ---- epilogue: segment-uniform per block (BN divides 1024) ----
    const int seg = n0 >> 10;  // 0=Q 1=K 2=V (mode 0); 0 for mode 1
    const float* bias = (mode == 1) ? b0 : (seg == 0 ? b0 : (seg == 1 ? b1 : b2));
    const float scale = (mode == 0 && seg == 0) ? 0.125f : 1.0f;
    const int nbase = (n0 & 1023) + wc * (BNT2 * 16);

    float bvals[BNT2];
#pragma unroll
    for (int nt = 0; nt < BNT2; ++nt)
        bvals[nt] = bias[nbase + nt * 16 + (lane & 15)];

#pragma unroll
    for (int mt = 0; mt < 4; ++mt)
#pragma unroll
        for (int nt = 0; nt < BNT2; ++nt)
#pragma unroll
            for (int i = 0; i < 4; ++i) {
                float v = (acc[mt][nt][i] + bvals[nt]) * scale;
                int m = m0 + wr * 64 + mt * 16 + (lane >> 4) * 4 + i;
                int n = nbase + nt * 16 + (lane & 15);  // within-segment col
                if (mode == 1) {
                    Fo[(size_t)m * HID + n] = v;
                } else if (seg == 0) {
                    Qo[(size_t)m * HID + n] = f2bf(v);
                } else if (seg == 1) {
                    Ko[(size_t)m * HID + n] = f2bf(v);
                } else {
                    Vo[(size_t)n * MROWS + (m & 1) * SEQ + (m >> 1)] = f2bf(v);
                }
            }
}

// ---------------------------------------------------------------------------
// Flash causal attention, bf16 MFMA — R5-exact revert (measured 79.5us).
// Grid (16, 32) = 512 uniform blocks; block handles q-tiles (31-p) then (p):
// exactly 33 tile-iterations each -> no causal/CU imbalance (R6 post-mortem:
// one-q-tile-per-block puts equal-qt blocks on the same CU -> 4x convoy).
// K/V double-buffered, global_load_lds with pre-swizzled source; one
// __syncthreads()/iter; XCD-clustered bh mapping.
// ---------------------------------------------------------------------------
__global__ __launch_bounds__(256) void attn_mfma(const unsigned short* __restrict__ Qb,
                                                 const unsigned short* __restrict__ Kb,
                                                 const unsigned short* __restrict__ Vt,
                                                 unsigned short* __restrict__ Ob) {
    __shared__ unsigned short Kl[2][64 * 64];  // [j][d] swizzled, 8KB each
    __shared__ unsigned short Vl[2][64 * 64];  // [d][j] swizzled, 8KB each
    __shared__ unsigned short QP[64 * 64];     // Q then P, swizzled, 8KB

    const int t = threadIdx.x;
    const int lane = t & 63, w = t >> 6;

    const int flat = (int)blockIdx.x + (int)blockIdx.y * 16;
    const int xcd = flat & 7, ii = flat >> 3;
    const int bh = xcd * 4 + (ii >> 4);
    const int p = ii & 15;
    const int b = bh >> 4, h = bh & 15;

    const int lrow_base = w * 8 + (lane >> 3);
    const int chunkb = (lane & 7) * 16;

    for (int pass = 0; pass < 2; ++pass) {
        const int qt = pass == 0 ? (31 - p) : p;
        const int q0 = qt * 64;
        if (pass) __syncthreads();

        auto stage_kv = [&](int buf, int kt) {
            const int k0 = kt * 64;
#pragma unroll
            for (int c = 0; c < 2; ++c) {
                int lr = c * 32 + lrow_base;
                int sb = chunkb ^ ((lr & 7) << 4);
                const unsigned short* ksrc =
                    Kb + ((size_t)(k0 + lr) * 2 + b) * HID + h * 64 + (sb >> 1);
                const unsigned short* vsrc =
                    Vt + (size_t)(h * 64 + lr) * MROWS + b * SEQ + k0 + (sb >> 1);
                __builtin_amdgcn_global_load_lds((gas_t)ksrc,
                    (las_t)(&Kl[buf][(c * 32 + w * 8) * 64]), 16, 0, 0);
                __builtin_amdgcn_global_load_lds((gas_t)vsrc,
                    (las_t)(&Vl[buf][(c * 32 + w * 8) * 64]), 16, 0, 0);
            }
        };

        stage_kv(0, 0);

#pragma unroll
        for (int c = 0; c < 2; ++c) {
            int f = c * 256 + t;
            int r = f >> 3, dc = f & 7;
            uint4 v = *(const uint4*)(Qb + (size_t)((q0 + r) * 2 + b) * HID + h * 64 + dc * 8);
            *(uint4*)((char*)QP + r * 128 + ((dc * 16) ^ ((r & 7) << 4))) = v;
        }

        f32x4 acc[4];
#pragma unroll
        for (int nt = 0; nt < 4; ++nt) acc[nt] = {0.f, 0.f, 0.f, 0.f};
        float mrow[4] = {-INFINITY, -INFINITY, -INFINITY, -INFINITY};
        float lrow[4] = {0.f, 0.f, 0.f, 0.f};
        bf16x8 qf[2];

        int cur = 0;
        for (int kt = 0; kt <= qt; ++kt) {
            __syncthreads();
            if (kt < qt) stage_kv(cur ^ 1, kt + 1);
            if (kt == 0) {
                int r = w * 16 + (lane & 15);
                int base = r * 128, sw = (r & 7) << 4;
                qf[0] = *(const bf16x8*)((char*)QP + base + ((((lane >> 4) * 16) + 0) ^ sw));
                qf[1] = *(const bf16x8*)((char*)QP + base + ((((lane >> 4) * 16) + 64) ^ sw));
            }
            const char* Kc = (const char*)Kl[cur];
            const char* Vc = (const char*)Vl[cur];

            f32x4 s[4];
#pragma unroll
            for (int ct = 0; ct < 4; ++ct) {
                int j = ct * 16 + (lane & 15);
                int base = j * 128, sw = (j & 7) << 4;
                bf16x8 kf0 = *(const bf16x8*)(Kc + base + ((((lane >> 4) * 16) + 0) ^ sw));
                bf16x8 kf1 = *(const bf16x8*)(Kc + base + ((((lane >> 4) * 16) + 64) ^ sw));
                f32x4 z = {0.f, 0.f, 0.f, 0.f};
                z = __builtin_amdgcn_mfma_f32_16x16x32_bf16(qf[0], kf0, z, 0, 0, 0);
                z = __builtin_amdgcn_mfma_f32_16x16x32_bf16(qf[1], kf1, z, 0, 0, 0);
                s[ct] = z;
            }

            if (kt == qt) {
#pragma unroll
                for (int ct = 0; ct < 4; ++ct) {
                    int j = ct * 16 + (lane & 15);
#pragma unroll
                    for (int i = 0; i < 4; ++i) {
                        int q = w * 16 + (lane >> 4) * 4 + i;
                        if (j > q) s[ct][i] = -3.0e38f;
                    }
                }
            }

#pragma unroll
            for (int i = 0; i < 4; ++i) {
                float mx = fmaxf(fmaxf(s[0][i], s[1][i]), fmaxf(s[2][i], s[3][i]));
                mx = fmaxf(mx, __shfl_xor(mx, 1));
                mx = fmaxf(mx, __shfl_xor(mx, 2));
                mx = fmaxf(mx, __shfl_xor(mx, 4));
                mx = fmaxf(mx, __shfl_xor(mx, 8));
                float mn = fmaxf(mrow[i], mx);
                float corr = __expf(mrow[i] - mn);
                mrow[i] = mn;
                float rs = 0.f;
#pragma unroll
                for (int ct = 0; ct < 4; ++ct) {
                    float pe = __expf(s[ct][i] - mn);
                    s[ct][i] = pe;
                    rs += pe;
                }
                rs += __shfl_xor(rs, 1);
                rs += __shfl_xor(rs, 2);
                rs += __shfl_xor(rs, 4);
                rs += __shfl_xor(rs, 8);
                lrow[i] = lrow[i] * corr + rs;
#pragma unroll
                for (int nt = 0; nt < 4; ++nt) acc[nt][i] *= corr;
            }

#pragma unroll
            for (int ct = 0; ct < 4; ++ct)
#pragma unroll
                for (int i = 0; i < 4; ++i) {
                    int r = w * 16 + (lane >> 4) * 4 + i;
                    int jb = (ct * 16 + (lane & 15)) * 2;
                    *(unsigned short*)((char*)QP + r * 128 + (jb ^ ((r & 7) << 4))) = f2bf(s[ct][i]);
                }
            asm volatile("s_waitcnt lgkmcnt(0)" ::: "memory");
            __builtin_amdgcn_sched_barrier(0);

            bf16x8 pf[2];
            {
                int r = w * 16 + (lane & 15);
                int base = r * 128, sw = (r & 7) << 4;
                pf[0] = *(const bf16x8*)((char*)QP + base + ((((lane >> 4) * 16) + 0) ^ sw));
                pf[1] = *(const bf16x8*)((char*)QP + base + ((((lane >> 4) * 16) + 64) ^ sw));
            }
#pragma unroll
            for (int nt = 0; nt < 4; ++nt) {
                int dd = nt * 16 + (lane & 15);
                int base = dd * 128, sw = (dd & 7) << 4;
                bf16x8 v0 = *(const bf16x8*)(Vc + base + ((((lane >> 4) * 16) + 0) ^ sw));
                bf16x8 v1 = *(const bf16x8*)(Vc + base + ((((lane >> 4) * 16) + 64) ^ sw));
                acc[nt] = __builtin_amdgcn_mfma_f32_16x16x32_bf16(pf[0], v0, acc[nt], 0, 0, 0);
                acc[nt] = __builtin_amdgcn_mfma_f32_16x16x32_bf16(pf[1], v1, acc[nt], 0, 0, 0);
            }
            cur ^= 1;
        }

#pragma unroll
        for (int i = 0; i < 4; ++i) {
            float inv = 1.0f / lrow[i];
            int q = q0 + w * 16 + (lane >> 4) * 4 + i;
#pragma unroll
            for (int nt = 0; nt < 4; ++nt) {
                int col = h * 64 + nt * 16 + (lane & 15);
                Ob[(size_t)(q * 2 + b) * HID + col] = f2bf(acc[nt][i] * inv);
            }
        }
    }
}

// ---------------------------------------------------------------------------
// Workspace (48 MB): hs_bf 8 | Wqkv_bf 6 | Wo_bf 2 | Q_bf 8 | K_bf 8 |
// Vt_bf 8 | ctx_bf 8
// ---------------------------------------------------------------------------
extern "C" void kernel_launch(void* const* d_in, const int* in_sizes, int n_in,
                              void* d_out, int out_size, void* d_ws, size_t ws_size,
                              hipStream_t stream) {
    const float* hs = (const float*)d_in[0];
    const float* Wq = (const float*)d_in[2];
    const float* bq = (const float*)d_in[3];
    const float* Wk = (const float*)d_in[4];
    const float* bk = (const float*)d_in[5];
    const float* Wv = (const float*)d_in[6];
    const float* bv = (const float*)d_in[7];
    const float* Wo = (const float*)d_in[8];
    const float* bo = (const float*)d_in[9];

    char* ws = (char*)d_ws;
    unsigned short* hs_bf   = (unsigned short*)(ws);
    unsigned short* Wqkv_bf = (unsigned short*)(ws + (8u << 20));   // 3072x1024
    unsigned short* Wo_bf   = (unsigned short*)(ws + (14u << 20));
    unsigned short* Q_bf    = (unsigned short*)(ws + (16u << 20));
    unsigned short* K_bf    = (unsigned short*)(ws + (24u << 20));
    unsigned short* Vt_bf   = (unsigned short*)(ws + (32u << 20));
    unsigned short* ctx_bf  = (unsigned short*)(ws + (40u << 20));

    dim3 blk(256);
    const int WN8 = HID * HID / 8;
    hipLaunchKernelGGL(f2bf_kern, dim3(MROWS * HID / 8 / 256), blk, 0, stream, hs, hs_bf, MROWS * HID / 8);
    hipLaunchKernelGGL(f2bf_kern, dim3(WN8 / 256), blk, 0, stream, Wq, Wqkv_bf, WN8);
    hipLaunchKernelGGL(f2bf_kern, dim3(WN8 / 256), blk, 0, stream, Wk, Wqkv_bf + (size_t)HID * HID, WN8);
    hipLaunchKernelGGL(f2bf_kern, dim3(WN8 / 256), blk, 0, stream, Wv, Wqkv_bf + (size_t)2 * HID * HID, WN8);
    hipLaunchKernelGGL(f2bf_kern, dim3(WN8 / 256), blk, 0, stream, Wo, Wo_bf, WN8);

    // fused QKV projection: BM=BN=128, grid (32,24) = 768 blocks
    hipLaunchKernelGGL((gemm_bf16<4>), dim3(MROWS / 128, 24), blk, 0, stream,
                       hs_bf, Wqkv_bf, bq, bk, bv, Q_bf, K_bf, Vt_bf, (float*)nullptr, 0);

    hipLaunchKernelGGL(attn_mfma, dim3(16, 32), blk, 0, stream,
                       Q_bf, K_bf, Vt_bf, ctx_bf);

    // output projection: BM=128 BN=64, grid (32,16) = 512 blocks
    hipLaunchKernelGGL((gemm_bf16<2>), dim3(MROWS / 128, 16), blk, 0, stream,
                       ctx_bf, Wo_bf, bo, bo, bo,
                       (unsigned short*)nullptr, (unsigned short*)nullptr,
                       (unsigned short*)nullptr, (float*)d_out, 1);
}